// Round 5
// baseline (86.585 us; speedup 1.0000x reference)
//
#include <hip/hip_runtime.h>

#define T 128
#define L2E 1.4426950408889634f   // log2(e)
#define LN2F 0.6931471805599453f  // ln(2)

typedef _Float16 h2 __attribute__((ext_vector_type(2)));

// lane l <- lane l-1; lane 0 <- 0   (DPP wave_shr:1, bound_ctrl=0)
__device__ __forceinline__ float shr1(float x) {
    return __int_as_float(__builtin_amdgcn_update_dpp(
        0, __float_as_int(x), 0x138, 0xF, 0xF, true));
}

template <int CTRL>
__device__ __forceinline__ float dppmax(float x) {
    float t = __int_as_float(__builtin_amdgcn_update_dpp(
        __float_as_int(x), __float_as_int(x), CTRL, 0xF, 0xF, false));
    return fmaxf(x, t);
}

struct RowR { float u, v, w, z, s; };   // 4x packed f16-pair + f32 sq

__device__ __forceinline__ float dot2(h2 x, float ybits, float acc) {
    return __builtin_amdgcn_fdot2(x, __builtin_bit_cast(h2, ybits), acc, false);
}

__launch_bounds__(256)
__global__ void sdtw_kernel(const float* __restrict__ X,
                            const float* __restrict__ Y,
                            float* __restrict__ out) {
    // Per wave: rows r in [0,385], row r holds y-row j = r-126 (valid j in [0,127],
    // else sentinel E=0). Parity-split SoA: parity P = r&1, h = r>>1 in [0,195].
    // Region per parity: U[196] V[196] W[196] Z[196] S[196] = 980 dwords.
    // Lane-stride through each array is 1 dword -> conflict-free LDS.
    __shared__ float lds[4 * 1960];
    const int lane = threadIdx.x & 63;
    const int w    = threadIdx.x >> 6;
    const int pair = blockIdx.x * 4 + w;   // 512 blocks * 4 waves = 2048 pairs
    const int a = pair >> 4;               // X index
    const int b = pair & 15;               // Y index

    float* E = lds + w * 1960;        // even-parity region
    float* O = E + 980;               // odd-parity region

    // ---- stage Y[b]: y' = 2*L2E*y (f16 pairs), sq = -L2E*|y|^2; sentinels ----
    {
        const float* ybase = Y + (size_t)b * T * 8;
        for (int r = lane; r < 386; r += 64) {
            float4 pk; pk.x = 0.f; pk.y = 0.f; pk.z = 0.f; pk.w = 0.f;
            float sq = -3.0e37f;
            int j = r - 126;
            if (j >= 0 && j < T) {
                const float4* src = (const float4*)(ybase + j * 8);
                float4 y0 = src[0], y1 = src[1];
                float s = y0.x*y0.x + y0.y*y0.y + y0.z*y0.z + y0.w*y0.w
                        + y1.x*y1.x + y1.y*y1.y + y1.z*y1.z + y1.w*y1.w;
                const float c = 2.0f * L2E;
                h2 a0 = { (_Float16)(c*y0.x), (_Float16)(c*y0.y) };
                h2 a1 = { (_Float16)(c*y0.z), (_Float16)(c*y0.w) };
                h2 a2 = { (_Float16)(c*y1.x), (_Float16)(c*y1.y) };
                h2 a3 = { (_Float16)(c*y1.z), (_Float16)(c*y1.w) };
                pk.x = __builtin_bit_cast(float, a0);
                pk.y = __builtin_bit_cast(float, a1);
                pk.z = __builtin_bit_cast(float, a2);
                pk.w = __builtin_bit_cast(float, a3);
                sq = -L2E * s;
            }
            float* reg = (r & 1) ? O : E;
            int h = r >> 1;
            reg[h]       = pk.x;
            reg[196 + h] = pk.y;
            reg[392 + h] = pk.z;
            reg[588 + h] = pk.w;
            reg[784 + h] = sq;
        }
    }

    // ---- X rows 2l (even) and 2l+1 (odd) for this lane ----
    h2 xe0, xe1, xe2, xe3, xo0, xo1, xo2, xo3;
    float lsxe, lsxo;
    {
        const float* xb = X + ((size_t)a * T + 2 * lane) * 8;
        const float4* s0p = (const float4*)xb;
        float4 v0 = s0p[0], v1 = s0p[1], u0 = s0p[2], u1 = s0p[3];
        xe0 = h2{ (_Float16)v0.x, (_Float16)v0.y };
        xe1 = h2{ (_Float16)v0.z, (_Float16)v0.w };
        xe2 = h2{ (_Float16)v1.x, (_Float16)v1.y };
        xe3 = h2{ (_Float16)v1.z, (_Float16)v1.w };
        lsxe = -L2E * (v0.x*v0.x+v0.y*v0.y+v0.z*v0.z+v0.w*v0.w
                      +v1.x*v1.x+v1.y*v1.y+v1.z*v1.z+v1.w*v1.w);
        xo0 = h2{ (_Float16)u0.x, (_Float16)u0.y };
        xo1 = h2{ (_Float16)u0.z, (_Float16)u0.w };
        xo2 = h2{ (_Float16)u1.x, (_Float16)u1.y };
        xo3 = h2{ (_Float16)u1.z, (_Float16)u1.w };
        lsxo = -L2E * (u0.x*u0.x+u0.y*u0.y+u0.z*u0.z+u0.w*u0.w
                      +u1.x*u1.x+u1.y*u1.y+u1.z*u1.z+u1.w*u1.w);
    }

    __syncthreads();

#define FETCH(SL, B, C) {            \
    SL.u = (B)[(C)];                 \
    SL.v = (B)[196 + (C)];           \
    SL.w = (B)[392 + (C)];           \
    SL.z = (B)[588 + (C)];           \
    SL.s = (B)[784 + (C)];           \
}

    // ---- prime ring: slot k holds row r = 126-2l+k  (k=0..7) ----
    RowR s0, s1, s2, s3, s4, s5, s6, s7;
    {
        int h0 = 63 - lane;
        FETCH(s0, E, h0);     FETCH(s1, O, h0);
        FETCH(s2, E, h0 + 1); FETCH(s3, O, h0 + 1);
        FETCH(s4, E, h0 + 2); FETCH(s5, O, h0 + 2);
        FETCH(s6, E, h0 + 3); FETCH(s7, O, h0 + 3);
    }
    const float* pe = E + (67 - lane);   // fetch base, even rows (h advances 1/2 bodies)
    const float* po = O + (67 - lane);   // fetch base, odd rows

    // ---- p = 0: even cell (0,0), lane 0 only (sentinels zero the rest) ----
    float fe0 = 0.f, fo0 = 0.f, fo1 = 0.f;
    int off = 90;
    float fe1;
    {
        float acc = lsxe + s0.s;
        acc = dot2(xe0, s0.u, acc);
        acc = dot2(xe1, s0.v, acc);
        acc = dot2(xe2, s0.w, acc);
        acc = dot2(xe3, s0.z, acc);
        fe1 = __builtin_amdgcn_exp2f(acc) * 0x1p90f;
    }

    // BODY: PE1/PO1 = p-1 state, PE2/PO2 = p-2 state (overwritten with new).
    // RO = row p+125-2l (odd cell), RE = row p+126-2l (even cell).
#define BODY(PE1, PE2, PO1, PO2, RO, RE) {              \
    float sB = shr1(PO1);                               \
    float sA = shr1(PO2);                               \
    float ae = lsxe + RE.s;                             \
    ae = dot2(xe0, RE.u, ae);                           \
    ae = dot2(xe1, RE.v, ae);                           \
    ae = dot2(xe2, RE.w, ae);                           \
    ae = dot2(xe3, RE.z, ae);                           \
    float ao = lsxo + RO.s;                             \
    ao = dot2(xo0, RO.u, ao);                           \
    ao = dot2(xo1, RO.v, ao);                           \
    ao = dot2(xo2, RO.w, ao);                           \
    ao = dot2(xo3, RO.z, ao);                           \
    float Ee = __builtin_amdgcn_exp2f(ae);              \
    float Eo = __builtin_amdgcn_exp2f(ao);              \
    float Se = Ee * ((sA + sB) + PE1);                  \
    float So = Eo * ((PE2 + PE1) + PO1);                \
    PE2 = Se; PO2 = So;                                 \
}

#define RENORM() {                                                            \
    float mx = fmaxf(fmaxf(fe0, fe1), fmaxf(fo0, fo1));                       \
    mx = dppmax<0x111>(mx);  /* row_shr:1 */                                  \
    mx = dppmax<0x112>(mx);  /* row_shr:2 */                                  \
    mx = dppmax<0x114>(mx);  /* row_shr:4 */                                  \
    mx = dppmax<0x118>(mx);  /* row_shr:8 */                                  \
    int r0_ = __builtin_amdgcn_readlane(__float_as_int(mx), 15);              \
    int r1_ = __builtin_amdgcn_readlane(__float_as_int(mx), 31);              \
    int r2_ = __builtin_amdgcn_readlane(__float_as_int(mx), 47);              \
    int r3_ = __builtin_amdgcn_readlane(__float_as_int(mx), 63);              \
    int mb = max(max(r0_, r1_), max(r2_, r3_));                               \
    int e = ((mb >> 23) & 0xff) - 217;   /* renorm max to 2^90 */             \
    fe0 = ldexpf(fe0, -e); fe1 = ldexpf(fe1, -e);                             \
    fo0 = ldexpf(fo0, -e); fo1 = ldexpf(fo1, -e);                             \
    off -= e;                                                                 \
}

    // p = 1..248: 31 iterations of 8 bodies (ring-8, state-2, renorm-4 all align)
    for (int it = 0; it < 31; ++it) {
        BODY(fe1, fe0, fo1, fo0, s0, s1); FETCH(s0, pe, 0);   // p=8it+1, fetch row p+7
        BODY(fe0, fe1, fo0, fo1, s1, s2); FETCH(s1, po, 0);
        BODY(fe1, fe0, fo1, fo0, s2, s3); FETCH(s2, pe, 1);
        BODY(fe0, fe1, fo0, fo1, s3, s4); FETCH(s3, po, 1);
        RENORM();
        BODY(fe1, fe0, fo1, fo0, s4, s5); FETCH(s4, pe, 2);
        BODY(fe0, fe1, fo0, fo1, s5, s6); FETCH(s5, po, 2);
        BODY(fe1, fe0, fo1, fo0, s6, s7); FETCH(s6, pe, 3);
        BODY(fe0, fe1, fo0, fo1, s7, s0); FETCH(s7, po, 3);
        RENORM();
        pe += 4; po += 4;
    }
    // p = 249..252 (+renorm), then tail p = 253, 254 (no fetch needed)
    BODY(fe1, fe0, fo1, fo0, s0, s1); FETCH(s0, pe, 0);
    BODY(fe0, fe1, fo0, fo1, s1, s2); FETCH(s1, po, 0);
    BODY(fe1, fe0, fo1, fo0, s2, s3); FETCH(s2, pe, 1);
    BODY(fe0, fe1, fo0, fo1, s3, s4); FETCH(s3, po, 1);
    RENORM();
    BODY(fe1, fe0, fo1, fo0, s4, s5);   // p = 253
    BODY(fe0, fe1, fo0, fo1, s5, s6);   // p = 254 -> new So in fo1

    // final cell (127,127) = odd row of lane 63: R = (off - log2(S)) * ln2
    if (lane == 63)
        out[pair] = ((float)off - __builtin_amdgcn_logf(fo1)) * LN2F;
}

extern "C" void kernel_launch(void* const* d_in, const int* in_sizes, int n_in,
                              void* d_out, int out_size, void* d_ws, size_t ws_size,
                              hipStream_t stream) {
    const float* X = (const float*)d_in[0];   // (128,128,8) f32
    const float* Y = (const float*)d_in[1];   // (16,128,8) f32
    float* out = (float*)d_out;               // (128,16) f32
    sdtw_kernel<<<512, 256, 0, stream>>>(X, Y, out);
}